// Round 1
// baseline (466.044 us; speedup 1.0000x reference)
//
#include <hip/hip_runtime.h>
#include <math.h>

#define BB 32
#define CC 256
#define HH 56
#define WW 56
#define KP 49      // 7*7 output pixels of the small convs
#define CMID 64    // C // RED
#define HW 3136    // 56*56

// ---------------- K1: adaptive avg pool 56x56 -> 7x7 per (b,c) ----------------
__global__ __launch_bounds__(256) void pool_kernel(const float* __restrict__ x,
                                                   float* __restrict__ pooled) {
    int c = blockIdx.x, b = blockIdx.y;
    __shared__ float plane[HW];
    const float* xp = x + ((size_t)(b * CC + c)) * HW;
    for (int e = threadIdx.x; e < HW; e += 256) plane[e] = xp[e];
    __syncthreads();
    int t = threadIdx.x;
    if (t < KP) {
        int ko = t / 7, kw = t % 7;
        float s = 0.f;
        #pragma unroll
        for (int r = 0; r < 8; ++r) {
            const float* row = plane + (ko * 8 + r) * WW + kw * 8;
            #pragma unroll
            for (int i = 0; i < 8; ++i) s += row[i];
        }
        pooled[((size_t)(b * CC + c)) * KP + t] = s * (1.f / 64.f);
    }
}

// ------------- K2: conv3x3 (256->64) + BN(inference) + exact GELU -------------
// grid (64 cout, 32 b), 256 threads = 4 waves; wave w reduces cin chunk [64w,64w+64)
__global__ __launch_bounds__(256) void conv1_kernel(const float* __restrict__ pooled,
                                                    const float* __restrict__ w1,
                                                    const float* __restrict__ gamma,
                                                    const float* __restrict__ beta,
                                                    float* __restrict__ hmid) {
    int co = blockIdx.x, b = blockIdx.y;
    __shared__ float ps[CC * KP];   // 12544 floats = 50 KB
    __shared__ float red[256];
    const float* pb = pooled + (size_t)b * CC * KP;
    for (int e = threadIdx.x; e < CC * KP; e += 256) ps[e] = pb[e];
    __syncthreads();
    int wv = threadIdx.x >> 6, lane = threadIdx.x & 63;
    float acc = 0.f;
    if (lane < KP) {
        int y = lane / 7, xx = lane % 7;
        int cin0 = wv * 64;
        for (int ci = 0; ci < 64; ++ci) {
            int cin = cin0 + ci;
            const float* wp = w1 + ((size_t)co * CC + cin) * 9;  // wave-uniform -> s_load
            const float* pp = ps + cin * KP;
            #pragma unroll
            for (int ky = 0; ky < 3; ++ky) {
                int iy = y + ky - 1;
                if ((unsigned)iy < 7u) {
                    #pragma unroll
                    for (int kx = 0; kx < 3; ++kx) {
                        int ix = xx + kx - 1;
                        if ((unsigned)ix < 7u)
                            acc += pp[iy * 7 + ix] * wp[ky * 3 + kx];
                    }
                }
            }
        }
    }
    red[threadIdx.x] = acc;
    __syncthreads();
    if (threadIdx.x < KP) {
        float tot = red[threadIdx.x] + red[threadIdx.x + 64] +
                    red[threadIdx.x + 128] + red[threadIdx.x + 192];
        float bnscale = gamma[co] * rsqrtf(1.f + 1e-5f);
        float h = tot * bnscale + beta[co];
        float g = 0.5f * h * (1.f + erff(h * 0.70710678118654752440f));
        hmid[((size_t)b * CMID + co) * KP + threadIdx.x] = g;
    }
}

// ------ K3: conv3x3 (64->512) + bias + softmax over G=2 + dyn kernel mix ------
// grid (64, 32), 256 threads; wave w handles c = blockIdx.x*4 + w, lane = pixel.
__global__ __launch_bounds__(256) void conv2_kernel(const float* __restrict__ hmid,
                                                    const float* __restrict__ w2,
                                                    const float* __restrict__ b2,
                                                    const float* __restrict__ wdyn,
                                                    float* __restrict__ dynw) {
    int b = blockIdx.y;
    int c = blockIdx.x * 4 + (threadIdx.x >> 6);
    int lane = threadIdx.x & 63;
    __shared__ float hs[CMID * KP];  // 3136 floats
    const float* hb = hmid + (size_t)b * CMID * KP;
    for (int e = threadIdx.x; e < CMID * KP; e += 256) hs[e] = hb[e];
    __syncthreads();
    if (lane < KP) {
        int y = lane / 7, xx = lane % 7;
        const float* w0 = w2 + (size_t)c * 576;          // wave-uniform -> s_load
        const float* w1 = w2 + (size_t)(c + CC) * 576;
        float s0 = b2[c], s1 = b2[c + CC];
        for (int cin = 0; cin < CMID; ++cin) {
            const float* hp = hs + cin * KP;
            const float* w0p = w0 + cin * 9;
            const float* w1p = w1 + cin * 9;
            #pragma unroll
            for (int ky = 0; ky < 3; ++ky) {
                int iy = y + ky - 1;
                if ((unsigned)iy < 7u) {
                    #pragma unroll
                    for (int kx = 0; kx < 3; ++kx) {
                        int ix = xx + kx - 1;
                        if ((unsigned)ix < 7u) {
                            float v = hp[iy * 7 + ix];
                            s0 += v * w0p[ky * 3 + kx];
                            s1 += v * w1p[ky * 3 + kx];
                        }
                    }
                }
            }
        }
        float m = fmaxf(s0, s1);
        float e0 = expf(s0 - m), e1 = expf(s1 - m);
        float inv = 1.f / (e0 + e1);
        float p0 = e0 * inv, p1 = e1 * inv;
        size_t o = ((size_t)(b * CC + c)) * KP + lane;
        dynw[o] = p0 * wdyn[c * KP + lane] + p1 * wdyn[CC * KP + c * KP + lane];
    }
}

// --------- K4: depthwise 7x7, pad 3, per-(b,c) dynamic kernel ---------
// grid (256 c, 32 b), 256 threads; threads 0..195 each own a 4x4 output tile.
__global__ __launch_bounds__(256) void dwconv_kernel(const float* __restrict__ x,
                                                     const float* __restrict__ dynw,
                                                     float* __restrict__ out) {
    int c = blockIdx.x, b = blockIdx.y;
    __shared__ float xs[62 * 63];    // padded plane, stride 63 (odd) vs bank conflicts
    const size_t base = ((size_t)(b * CC + c)) * HW;
    const float* xp = x + base;
    for (int e = threadIdx.x; e < 62 * 63; e += 256) xs[e] = 0.f;
    __syncthreads();
    for (int e = threadIdx.x; e < HW; e += 256) {
        int r = e / 56, col = e % 56;
        xs[(r + 3) * 63 + (col + 3)] = xp[e];
    }
    __syncthreads();
    // 49 weights via wave-uniform address -> scalar loads (SGPRs)
    const float* wp = dynw + ((size_t)(b * CC + c)) * KP;
    float w[49];
    #pragma unroll
    for (int i = 0; i < 49; ++i) w[i] = wp[i];
    if (threadIdx.x < 196) {
        int ty = threadIdx.x / 14, tx = threadIdx.x % 14;
        int r0 = ty * 4, c0 = tx * 4;
        float acc[4][4] = {};
        #pragma unroll
        for (int ir = 0; ir < 10; ++ir) {
            float rb[10];
            #pragma unroll
            for (int j = 0; j < 10; ++j) rb[j] = xs[(r0 + ir) * 63 + c0 + j];
            #pragma unroll
            for (int ky = 0; ky < 7; ++ky) {
                int oy = ir - ky;               // compile-time after full unroll
                if (oy >= 0 && oy < 4) {
                    #pragma unroll
                    for (int kx = 0; kx < 7; ++kx) {
                        float ww = w[ky * 7 + kx];
                        #pragma unroll
                        for (int ox = 0; ox < 4; ++ox)
                            acc[oy][ox] += rb[kx + ox] * ww;
                    }
                }
            }
        }
        float* op = out + base;
        #pragma unroll
        for (int i = 0; i < 4; ++i) {
            float4 v = make_float4(acc[i][0], acc[i][1], acc[i][2], acc[i][3]);
            *reinterpret_cast<float4*>(op + (r0 + i) * 56 + c0) = v;
        }
    }
}

extern "C" void kernel_launch(void* const* d_in, const int* in_sizes, int n_in,
                              void* d_out, int out_size, void* d_ws, size_t ws_size,
                              hipStream_t stream) {
    const float* x     = (const float*)d_in[0];  // (32,256,56,56)
    const float* wdyn  = (const float*)d_in[1];  // (2,256,7,7)
    const float* w1    = (const float*)d_in[2];  // (64,256,3,3)
    const float* gamma = (const float*)d_in[3];  // (64,)
    const float* beta  = (const float*)d_in[4];  // (64,)
    const float* w2    = (const float*)d_in[5];  // (512,64,3,3)
    const float* b2    = (const float*)d_in[6];  // (512,)
    float* out = (float*)d_out;

    float* ws     = (float*)d_ws;
    float* pooled = ws;              // 32*256*49 = 401408 floats
    float* hmid   = ws + 401408;     // 32*64*49  = 100352 floats
    float* dynw   = ws + 501760;     // 32*256*49 = 401408 floats

    pool_kernel <<<dim3(CC, BB),     256, 0, stream>>>(x, pooled);
    conv1_kernel<<<dim3(CMID, BB),   256, 0, stream>>>(pooled, w1, gamma, beta, hmid);
    conv2_kernel<<<dim3(CC / 4, BB), 256, 0, stream>>>(hmid, w2, b2, wdyn, dynw);
    dwconv_kernel<<<dim3(CC, BB),    256, 0, stream>>>(x, dynw, out);
}

// Round 2
// 379.085 us; speedup vs baseline: 1.2294x; 1.2294x over previous
//
#include <hip/hip_runtime.h>
#include <math.h>

#define BB 32
#define CC 256
#define HH 56
#define WW 56
#define KP 49      // 7*7 output pixels of the small convs
#define CMID 64    // C // RED
#define HW 3136    // 56*56

// -------- K0: transpose weights to channel-last for lane=cout coalescing -----
// w1 (64,256,9) -> w1t[(cin*9+t)*64 + co]   (147456 floats)
// w2 (512,64,9) -> w2t[(cin*9+t)*512 + co]  (294912 floats)
__global__ __launch_bounds__(256) void transpose_w_kernel(const float* __restrict__ w1,
                                                          const float* __restrict__ w2,
                                                          float* __restrict__ w1t,
                                                          float* __restrict__ w2t) {
    int tid = blockIdx.x * 256 + threadIdx.x;
    if (tid < 147456) {
        int co = tid & 63, ct = tid >> 6;
        w1t[tid] = w1[co * 2304 + ct];
    }
    if (tid < 294912) {
        int co = tid & 511, ct = tid >> 9;
        w2t[tid] = w2[co * 576 + ct];
    }
}

// ---------------- K1: adaptive avg pool 56x56 -> 7x7 per (b,c) ----------------
__global__ __launch_bounds__(256) void pool_kernel(const float* __restrict__ x,
                                                   float* __restrict__ pooled) {
    int c = blockIdx.x, b = blockIdx.y;
    __shared__ float plane[HW];
    __shared__ float ps[KP][4];
    const float4* xp4 = (const float4*)(x + ((size_t)(b * CC + c)) * HW);
    float4* pl4 = (float4*)plane;
    for (int e = threadIdx.x; e < HW / 4; e += 256) pl4[e] = xp4[e];
    __syncthreads();
    int t = threadIdx.x;
    if (t < 196) {
        int w = t >> 2, q = t & 3;          // window, quarter (2 rows each)
        int ko = w / 7, kw = w % 7;
        float s = 0.f;
        #pragma unroll
        for (int r = 0; r < 2; ++r) {
            const float* row = plane + (ko * 8 + q * 2 + r) * WW + kw * 8;
            float4 v0 = *(const float4*)(row);
            float4 v1 = *(const float4*)(row + 4);
            s += v0.x + v0.y + v0.z + v0.w + v1.x + v1.y + v1.z + v1.w;
        }
        ps[w][q] = s;
    }
    __syncthreads();
    if (t < KP) {
        float s = ps[t][0] + ps[t][1] + ps[t][2] + ps[t][3];
        pooled[((size_t)(b * CC + c)) * KP + t] = s * (1.f / 64.f);
    }
}

// ------------- K2: conv3x3 (256->64) + BN(inference) + exact GELU -------------
// grid (7 rows, 32 b), 256 threads: lane = cout (64), wave = cin chunk (4x64).
// Weights: coalesced vector loads from w1t. Activations: wave-uniform s_loads.
__global__ __launch_bounds__(256) void conv1_kernel(const float* __restrict__ pooled,
                                                    const float* __restrict__ w1t,
                                                    const float* __restrict__ gamma,
                                                    const float* __restrict__ beta,
                                                    float* __restrict__ hmid) {
    int y = blockIdx.x, b = blockIdx.y;
    int wv = threadIdx.x >> 6, co = threadIdx.x & 63;
    __shared__ float red[4][7][64];
    float acc[7] = {0.f, 0.f, 0.f, 0.f, 0.f, 0.f, 0.f};
    const float* pb = pooled + (size_t)b * CC * KP;
    for (int ci = 0; ci < 64; ++ci) {
        int cin = wv * 64 + ci;
        const float* prow_base = pb + cin * KP;
        const float* wbase = w1t + (size_t)(cin * 9) * 64 + co;
        #pragma unroll
        for (int ky = 0; ky < 3; ++ky) {
            int iy = y + ky - 1;
            if (0 <= iy && iy < 7) {                    // uniform branch
                float s[9];
                s[0] = 0.f; s[8] = 0.f;
                const float* pr = prow_base + iy * 7;   // uniform addr -> s_load
                #pragma unroll
                for (int j = 0; j < 7; ++j) s[j + 1] = pr[j];
                const float* wr = wbase + ky * 3 * 64;
                float w0 = wr[0], w1v = wr[64], w2v = wr[128];
                #pragma unroll
                for (int xx = 0; xx < 7; ++xx)
                    acc[xx] += s[xx] * w0 + s[xx + 1] * w1v + s[xx + 2] * w2v;
            }
        }
    }
    #pragma unroll
    for (int xx = 0; xx < 7; ++xx) red[wv][xx][co] = acc[xx];
    __syncthreads();
    for (int e = threadIdx.x; e < 448; e += 256) {
        int xx = e >> 6, c2 = e & 63;
        float tot = red[0][xx][c2] + red[1][xx][c2] + red[2][xx][c2] + red[3][xx][c2];
        float bnscale = gamma[c2] * rsqrtf(1.f + 1e-5f);
        float h = tot * bnscale + beta[c2];
        float g = 0.5f * h * (1.f + erff(h * 0.70710678118654752440f));
        hmid[((size_t)b * CMID + c2) * KP + y * 7 + xx] = g;
    }
}

// ------ K3: conv3x3 (64->512) + bias + softmax over G=2 + dyn kernel mix ------
// grid (7 rows, 32 b), 256 threads: thread co handles couts (co, co+256) — the
// softmax pair. Weights coalesced from w2t; activations via uniform s_loads.
__global__ __launch_bounds__(256) void conv2_kernel(const float* __restrict__ hmid,
                                                    const float* __restrict__ w2t,
                                                    const float* __restrict__ b2,
                                                    const float* __restrict__ wdyn,
                                                    float* __restrict__ dynw) {
    int y = blockIdx.x, b = blockIdx.y;
    int co = threadIdx.x;
    float a0[7], a1[7];
    float bias0 = b2[co], bias1 = b2[co + CC];
    #pragma unroll
    for (int xx = 0; xx < 7; ++xx) { a0[xx] = bias0; a1[xx] = bias1; }
    const float* hb = hmid + (size_t)b * CMID * KP;
    for (int cin = 0; cin < CMID; ++cin) {
        const float* hrow_base = hb + cin * KP;
        const float* wbase = w2t + (size_t)(cin * 9) * 512 + co;
        #pragma unroll
        for (int ky = 0; ky < 3; ++ky) {
            int iy = y + ky - 1;
            if (0 <= iy && iy < 7) {                    // uniform branch
                float s[9];
                s[0] = 0.f; s[8] = 0.f;
                const float* hr = hrow_base + iy * 7;   // uniform addr -> s_load
                #pragma unroll
                for (int j = 0; j < 7; ++j) s[j + 1] = hr[j];
                const float* wr = wbase + ky * 3 * 512;
                float wa0 = wr[0],    wb0 = wr[256];
                float wa1 = wr[512],  wb1 = wr[768];
                float wa2 = wr[1024], wb2 = wr[1280];
                #pragma unroll
                for (int xx = 0; xx < 7; ++xx) {
                    float v0 = s[xx], v1 = s[xx + 1], v2 = s[xx + 2];
                    a0[xx] += v0 * wa0 + v1 * wa1 + v2 * wa2;
                    a1[xx] += v0 * wb0 + v1 * wb1 + v2 * wb2;
                }
            }
        }
    }
    const float* wd0 = wdyn + (size_t)co * KP + y * 7;
    const float* wd1 = wdyn + (size_t)(CC + co) * KP + y * 7;
    float* dw = dynw + ((size_t)(b * CC + co)) * KP + y * 7;
    #pragma unroll
    for (int xx = 0; xx < 7; ++xx) {
        float m = fmaxf(a0[xx], a1[xx]);
        float e0 = expf(a0[xx] - m), e1 = expf(a1[xx] - m);
        float inv = 1.f / (e0 + e1);
        dw[xx] = (e0 * wd0[xx] + e1 * wd1[xx]) * inv;
    }
}

// --------- K4: depthwise 7x7, pad 3, per-(b,c) dynamic kernel ---------
__global__ __launch_bounds__(256) void dwconv_kernel(const float* __restrict__ x,
                                                     const float* __restrict__ dynw,
                                                     float* __restrict__ out) {
    int c = blockIdx.x, b = blockIdx.y;
    __shared__ float xs[62 * 63];    // padded plane, stride 63 (odd) vs bank conflicts
    const size_t base = ((size_t)(b * CC + c)) * HW;
    const float* xp = x + base;
    for (int e = threadIdx.x; e < 62 * 63; e += 256) xs[e] = 0.f;
    __syncthreads();
    for (int e = threadIdx.x; e < HW; e += 256) {
        int r = e / 56, col = e % 56;
        xs[(r + 3) * 63 + (col + 3)] = xp[e];
    }
    __syncthreads();
    const float* wp = dynw + ((size_t)(b * CC + c)) * KP;  // uniform -> s_load
    float w[49];
    #pragma unroll
    for (int i = 0; i < 49; ++i) w[i] = wp[i];
    if (threadIdx.x < 196) {
        int ty = threadIdx.x / 14, tx = threadIdx.x % 14;
        int r0 = ty * 4, c0 = tx * 4;
        float acc[4][4] = {};
        #pragma unroll
        for (int ir = 0; ir < 10; ++ir) {
            float rb[10];
            #pragma unroll
            for (int j = 0; j < 10; ++j) rb[j] = xs[(r0 + ir) * 63 + c0 + j];
            #pragma unroll
            for (int ky = 0; ky < 7; ++ky) {
                int oy = ir - ky;
                if (oy >= 0 && oy < 4) {
                    #pragma unroll
                    for (int kx = 0; kx < 7; ++kx) {
                        float ww = w[ky * 7 + kx];
                        #pragma unroll
                        for (int ox = 0; ox < 4; ++ox)
                            acc[oy][ox] += rb[kx + ox] * ww;
                    }
                }
            }
        }
        float* op = out + base;
        #pragma unroll
        for (int i = 0; i < 4; ++i) {
            float4 v = make_float4(acc[i][0], acc[i][1], acc[i][2], acc[i][3]);
            *reinterpret_cast<float4*>(op + (r0 + i) * 56 + c0) = v;
        }
    }
}

extern "C" void kernel_launch(void* const* d_in, const int* in_sizes, int n_in,
                              void* d_out, int out_size, void* d_ws, size_t ws_size,
                              hipStream_t stream) {
    const float* x     = (const float*)d_in[0];  // (32,256,56,56)
    const float* wdyn  = (const float*)d_in[1];  // (2,256,7,7)
    const float* w1    = (const float*)d_in[2];  // (64,256,3,3)
    const float* gamma = (const float*)d_in[3];  // (64,)
    const float* beta  = (const float*)d_in[4];  // (64,)
    const float* w2    = (const float*)d_in[5];  // (512,64,3,3)
    const float* b2    = (const float*)d_in[6];  // (512,)
    float* out = (float*)d_out;

    float* ws     = (float*)d_ws;
    float* pooled = ws;               // 401408 floats
    float* hmid   = ws + 401408;      // 100352 floats
    float* dynw   = ws + 501760;      // 401408 floats
    float* w1t    = ws + 903168;      // 147456 floats
    float* w2t    = ws + 1050624;     // 294912 floats  (total 1345536 = 5.2 MB)

    transpose_w_kernel<<<dim3(1152),   256, 0, stream>>>(w1, w2, w1t, w2t);
    pool_kernel       <<<dim3(CC, BB), 256, 0, stream>>>(x, pooled);
    conv1_kernel      <<<dim3(7, BB),  256, 0, stream>>>(pooled, w1t, gamma, beta, hmid);
    conv2_kernel      <<<dim3(7, BB),  256, 0, stream>>>(hmid, w2t, b2, wdyn, dynw);
    dwconv_kernel     <<<dim3(CC, BB), 256, 0, stream>>>(x, dynw, out);
}

// Round 3
// 322.306 us; speedup vs baseline: 1.4460x; 1.1762x over previous
//
#include <hip/hip_runtime.h>
#include <math.h>

#define BB 32
#define CC 256
#define HH 56
#define WW 56
#define KP 49      // 7*7 output pixels of the small convs
#define CMID 64    // C // RED
#define HW 3136    // 56*56

// dwconv LDS plane geometry: 62 padded rows, 64-word ring per row
#define RSTR 64
#define PROWS 62
#define PSZ (PROWS * RSTR)   // 3968 words per plane

// -------- K0: transpose weights to channel-last for lane=cout coalescing -----
__global__ __launch_bounds__(256) void transpose_w_kernel(const float* __restrict__ w1,
                                                          const float* __restrict__ w2,
                                                          float* __restrict__ w1t,
                                                          float* __restrict__ w2t) {
    int tid = blockIdx.x * 256 + threadIdx.x;
    if (tid < 147456) {
        int co = tid & 63, ct = tid >> 6;
        w1t[tid] = w1[co * 2304 + ct];
    }
    if (tid < 294912) {
        int co = tid & 511, ct = tid >> 9;
        w2t[tid] = w2[co * 576 + ct];
    }
}

// ------------- K1: adaptive avg pool, no LDS: wave = plane, lane = window -----
__global__ __launch_bounds__(256) void pool_kernel(const float* __restrict__ x,
                                                   float* __restrict__ pooled) {
    int wv = threadIdx.x >> 6, lane = threadIdx.x & 63;
    int g = blockIdx.x * 4 + wv;            // plane id = b*256 + c
    if (lane < KP) {
        int ko = lane / 7, kw = lane - ko * 7;
        const float* base = x + (size_t)g * HW + (ko * 8) * WW + kw * 8;
        float s = 0.f;
        #pragma unroll
        for (int r = 0; r < 8; ++r) {
            float4 a = *(const float4*)(base + r * WW);
            float4 b4 = *(const float4*)(base + r * WW + 4);
            s += a.x + a.y + a.z + a.w + b4.x + b4.y + b4.z + b4.w;
        }
        pooled[(size_t)g * KP + lane] = s * (1.f / 64.f);
    }
}

// ------------- K2: conv3x3 (256->64) + BN + exact GELU; 512 thr, 8-way cin ---
__global__ __launch_bounds__(512) void conv1_kernel(const float* __restrict__ pooled,
                                                    const float* __restrict__ w1t,
                                                    const float* __restrict__ gamma,
                                                    const float* __restrict__ beta,
                                                    float* __restrict__ hmid) {
    int y = blockIdx.x, b = blockIdx.y;
    int wv = threadIdx.x >> 6, co = threadIdx.x & 63;
    __shared__ float red[8][7][64];
    float acc[7] = {0.f, 0.f, 0.f, 0.f, 0.f, 0.f, 0.f};
    const float* pb = pooled + (size_t)b * CC * KP;
    for (int ci = 0; ci < 32; ++ci) {
        int cin = wv * 32 + ci;
        const float* prow_base = pb + cin * KP;
        const float* wbase = w1t + (size_t)(cin * 9) * 64 + co;
        #pragma unroll
        for (int ky = 0; ky < 3; ++ky) {
            int iy = y + ky - 1;
            if (0 <= iy && iy < 7) {                    // uniform branch
                float s[9];
                s[0] = 0.f; s[8] = 0.f;
                const float* pr = prow_base + iy * 7;   // uniform addr -> s_load
                #pragma unroll
                for (int j = 0; j < 7; ++j) s[j + 1] = pr[j];
                const float* wr = wbase + ky * 3 * 64;
                float w0 = wr[0], w1v = wr[64], w2v = wr[128];
                #pragma unroll
                for (int xx = 0; xx < 7; ++xx)
                    acc[xx] += s[xx] * w0 + s[xx + 1] * w1v + s[xx + 2] * w2v;
            }
        }
    }
    #pragma unroll
    for (int xx = 0; xx < 7; ++xx) red[wv][xx][co] = acc[xx];
    __syncthreads();
    if (threadIdx.x < 448) {
        int xx = threadIdx.x >> 6, c2 = threadIdx.x & 63;
        float tot = 0.f;
        #pragma unroll
        for (int w = 0; w < 8; ++w) tot += red[w][xx][c2];
        float bnscale = gamma[c2] * rsqrtf(1.f + 1e-5f);
        float h = tot * bnscale + beta[c2];
        float g = 0.5f * h * (1.f + erff(h * 0.70710678118654752440f));
        hmid[((size_t)b * CMID + c2) * KP + y * 7 + xx] = g;
    }
}

// ------ K3: conv3x3 (64->512) + bias + softmax + mix; 512 thr, 2-way cin -----
__global__ __launch_bounds__(512) void conv2_kernel(const float* __restrict__ hmid,
                                                    const float* __restrict__ w2t,
                                                    const float* __restrict__ b2,
                                                    const float* __restrict__ wdyn,
                                                    float* __restrict__ dynw) {
    int y = blockIdx.x, b = blockIdx.y;
    int g = threadIdx.x >> 8, co = threadIdx.x & 255;
    __shared__ float redA[2][7][256];
    __shared__ float redB[2][7][256];
    float a0[7] = {}, a1[7] = {};
    const float* hb = hmid + (size_t)b * CMID * KP;
    for (int ci = 0; ci < 32; ++ci) {
        int cin = g * 32 + ci;
        const float* hrow_base = hb + cin * KP;
        const float* wbase = w2t + (size_t)(cin * 9) * 512 + co;
        #pragma unroll
        for (int ky = 0; ky < 3; ++ky) {
            int iy = y + ky - 1;
            if (0 <= iy && iy < 7) {                    // uniform branch
                float s[9];
                s[0] = 0.f; s[8] = 0.f;
                const float* hr = hrow_base + iy * 7;   // uniform addr -> s_load
                #pragma unroll
                for (int j = 0; j < 7; ++j) s[j + 1] = hr[j];
                const float* wr = wbase + ky * 3 * 512;
                float wa0 = wr[0],    wb0 = wr[256];
                float wa1 = wr[512],  wb1 = wr[768];
                float wa2 = wr[1024], wb2 = wr[1280];
                #pragma unroll
                for (int xx = 0; xx < 7; ++xx) {
                    float v0 = s[xx], v1 = s[xx + 1], v2 = s[xx + 2];
                    a0[xx] += v0 * wa0 + v1 * wa1 + v2 * wa2;
                    a1[xx] += v0 * wb0 + v1 * wb1 + v2 * wb2;
                }
            }
        }
    }
    #pragma unroll
    for (int xx = 0; xx < 7; ++xx) { redA[g][xx][co] = a0[xx]; redB[g][xx][co] = a1[xx]; }
    __syncthreads();
    if (threadIdx.x < 256) {
        int c = threadIdx.x;
        float bias0 = b2[c], bias1 = b2[c + CC];
        const float* wd0 = wdyn + (size_t)c * KP + y * 7;
        const float* wd1 = wdyn + (size_t)(CC + c) * KP + y * 7;
        float* dw = dynw + ((size_t)(b * CC + c)) * KP + y * 7;
        #pragma unroll
        for (int xx = 0; xx < 7; ++xx) {
            float s0 = redA[0][xx][c] + redA[1][xx][c] + bias0;
            float s1 = redB[0][xx][c] + redB[1][xx][c] + bias1;
            float m = fmaxf(s0, s1);
            float e0 = expf(s0 - m), e1 = expf(s1 - m);
            dw[xx] = (e0 * wd0[xx] + e1 * wd1[xx]) / (e0 + e1);
        }
    }
}

// --------- K4: depthwise 7x7: 4 planes/block, wave=plane, 8x8 tiles ----------
// LDS ring layout: padded col d (0..61) of padded row pr stored at word
// (d + 1 + shift(pr)) & 63 within the row's 64-word ring, shift = 4*((pr>>3)&7).
// This makes ds_read_b128 bank groups (2*tx + ty') mod 8 -> near-uniform.
__global__ __launch_bounds__(256) void dwconv_kernel(const float* __restrict__ x,
                                                     const float* __restrict__ dynw,
                                                     float* __restrict__ out) {
    __shared__ float xs[4 * PSZ];           // 62 KB
    int tid = threadIdx.x;
    int g0 = blockIdx.x * 4;                // first plane id of this block

    // zero-fill (covers row pads and ring gaps)
    float4* xs4 = (float4*)xs;
    for (int e = tid; e < 4 * PSZ / 4; e += 256)
        xs4[e] = make_float4(0.f, 0.f, 0.f, 0.f);
    __syncthreads();

    // stage 4 planes: 56 rows x 14 float4 each, rotated ring placement
    for (int idx = tid; idx < 4 * 56 * 14; idx += 256) {
        int p   = idx / 784;
        int rem = idx - p * 784;
        int r   = rem / 14;
        int c4  = rem - r * 14;
        float4 v = *((const float4*)(x + ((size_t)(g0 + p)) * HW + r * WW) + c4);
        int pr    = r + 3;
        int shift = 4 * ((pr >> 3) & 7);
        int col   = (4 * c4 + 4 + shift) & 63;
        *(float4*)(xs + p * PSZ + pr * RSTR + col) = v;
    }
    __syncthreads();

    int wv = tid >> 6, lane = tid & 63;
    int gplane = __builtin_amdgcn_readfirstlane(g0 + wv);   // wave-uniform
    const float* wp = dynw + (size_t)gplane * KP;           // -> s_loads
    float w[49];
    #pragma unroll
    for (int i = 0; i < 49; ++i) w[i] = wp[i];

    if (lane < KP) {
        int ty = lane / 7, tx = lane - ty * 7;
        int r0 = 8 * ty, c0 = 8 * tx;       // output tile origin
        const float* pbase = xs + wv * PSZ;
        float acc[8][8] = {};
        #pragma unroll
        for (int ir = 0; ir < 14; ++ir) {
            int pr = r0 + ir;               // padded row 0..61
            int shift = 4 * ((pr >> 3) & 7);
            const float* rowp = pbase + pr * RSTR;
            float rb[16];
            #pragma unroll
            for (int k = 0; k < 4; ++k) {
                int col = (c0 + shift + 4 * k) & 63;
                float4 v = *(const float4*)(rowp + col);
                rb[4 * k + 0] = v.x; rb[4 * k + 1] = v.y;
                rb[4 * k + 2] = v.z; rb[4 * k + 3] = v.w;
            }
            // rb[i] holds padded col d = c0 + i - 1
            #pragma unroll
            for (int ky = 0; ky < 7; ++ky) {
                int oy = ir - ky;
                if (0 <= oy && oy < 8) {
                    #pragma unroll
                    for (int kx = 0; kx < 7; ++kx) {
                        float ww = w[ky * 7 + kx];
                        #pragma unroll
                        for (int ox = 0; ox < 8; ++ox)
                            acc[oy][ox] += rb[ox + 1 + kx] * ww;
                    }
                }
            }
        }
        float* op = out + (size_t)(g0 + wv) * HW;
        #pragma unroll
        for (int oy = 0; oy < 8; ++oy) {
            float* orow = op + (r0 + oy) * WW + c0;
            *(float4*)(orow)     = make_float4(acc[oy][0], acc[oy][1], acc[oy][2], acc[oy][3]);
            *(float4*)(orow + 4) = make_float4(acc[oy][4], acc[oy][5], acc[oy][6], acc[oy][7]);
        }
    }
}

extern "C" void kernel_launch(void* const* d_in, const int* in_sizes, int n_in,
                              void* d_out, int out_size, void* d_ws, size_t ws_size,
                              hipStream_t stream) {
    const float* x     = (const float*)d_in[0];  // (32,256,56,56)
    const float* wdyn  = (const float*)d_in[1];  // (2,256,7,7)
    const float* w1    = (const float*)d_in[2];  // (64,256,3,3)
    const float* gamma = (const float*)d_in[3];  // (64,)
    const float* beta  = (const float*)d_in[4];  // (64,)
    const float* w2    = (const float*)d_in[5];  // (512,64,3,3)
    const float* b2    = (const float*)d_in[6];  // (512,)
    float* out = (float*)d_out;

    float* ws     = (float*)d_ws;
    float* pooled = ws;               // 401408 floats
    float* hmid   = ws + 401408;      // 100352 floats
    float* dynw   = ws + 501760;      // 401408 floats
    float* w1t    = ws + 903168;      // 147456 floats
    float* w2t    = ws + 1050624;     // 294912 floats  (total 5.2 MB)

    transpose_w_kernel<<<dim3(1152),        256, 0, stream>>>(w1, w2, w1t, w2t);
    pool_kernel       <<<dim3(BB * CC / 4), 256, 0, stream>>>(x, pooled);
    conv1_kernel      <<<dim3(7, BB),       512, 0, stream>>>(pooled, w1t, gamma, beta, hmid);
    conv2_kernel      <<<dim3(7, BB),       512, 0, stream>>>(hmid, w2t, b2, wdyn, dynw);
    dwconv_kernel     <<<dim3(BB * CC / 4), 256, 0, stream>>>(x, dynw, out);
}